// Round 1
// baseline (236.361 us; speedup 1.0000x reference)
//
#include <hip/hip_runtime.h>

// Problem constants
#define BDIM   16
#define PDIM   12
#define TDIM   4096
#define WINW   41
#define PADW   20
#define DDIM   492      // P*WIN
#define DPAD   512      // padded K for MFMA (zeros beyond 492)
#define KCODES 1024
#define BM     64       // rows per block (4 waves x 16 rows)
#define KSTEPS 16       // 512 / 32
#define NTILES 64       // 1024 / 16

typedef __attribute__((ext_vector_type(8))) short  short8;  // 8 x bf16 (4 VGPRs)
typedef __attribute__((ext_vector_type(4))) float  f32x4;   // MFMA acc

__device__ __forceinline__ unsigned short f2bf(float f) {
    union { float f; unsigned int u; } v; v.f = f;
    unsigned int r = v.u + 0x7FFFu + ((v.u >> 16) & 1u);  // round-to-nearest-even
    return (unsigned short)(r >> 16);
}

// Pre-format codebook into B-fragment order for mfma_f32_16x16x32_bf16.
// Layout: frag index idx = (nt*16 + ks)*64 + lane, each holding 8 bf16:
//   B[k][n] with n = nt*16 + (lane&15), k = ks*32 + (lane>>4)*8 + j
__global__ __launch_bounds__(256) void prep_bfrag_k(const float* __restrict__ cb,
                                                    unsigned short* __restrict__ bfrag) {
    int idx  = blockIdx.x * 256 + threadIdx.x;   // 0 .. 65535
    int lane = idx & 63;
    int ks   = (idx >> 6) & 15;
    int nt   = idx >> 10;
    int n    = nt * 16 + (lane & 15);
    int hi   = lane >> 4;
    short8 sv;
#pragma unroll
    for (int j = 0; j < 8; ++j) {
        int k = ks * 32 + hi * 8 + j;
        float f = (k < DDIM) ? cb[n * DDIM + k] : 0.f;
        sv[j] = (short)f2bf(f);
    }
    *(short8*)(bfrag + (size_t)idx * 8) = sv;
}

__global__ __launch_bounds__(64) void prep_cnorm_k(const float* __restrict__ cb,
                                                   float* __restrict__ cnorm) {
    int n = blockIdx.x;
    int lane = threadIdx.x;
    float s = 0.f;
    for (int d = lane; d < DDIM; d += 64) { float c = cb[n * DDIM + d]; s += c * c; }
#pragma unroll
    for (int m = 1; m < 64; m <<= 1) s += __shfl_xor(s, m, 64);
    if (lane == 0) cnorm[n] = s;
}

// Main: per block of 64 rows, sweep all 1024 codes via MFMA, track per-row best
// score = f.c - 0.5*||c||^2 (argmax == argmin dist), then recompute the chosen
// distance exactly in fp32 and emit a per-block partial sum.
__global__ __launch_bounds__(256) void vq_main_k(const float* __restrict__ x,
                                                 const float* __restrict__ cb,
                                                 const unsigned short* __restrict__ bfrag,
                                                 const float* __restrict__ cnorm,
                                                 float* __restrict__ bsum) {
    const int lane = threadIdx.x & 63;
    const int wave = threadIdx.x >> 6;
    const int ld   = lane & 15;
    const int hi   = lane >> 4;
    const int rowbase = blockIdx.x * BM + wave * 16;

    // ---- Build A fragments (row = rowbase+ld, k = ks*32 + hi*8 + j) in regs ----
    short8 afr[KSTEPS];
    {
        int m = rowbase + ld;
        int b = m >> 12;            // / TDIM
        int t = m & (TDIM - 1);
        const float* xb = x + (size_t)b * (PDIM * TDIM);
#pragma unroll
        for (int ks = 0; ks < KSTEPS; ++ks) {
            short8 a;
#pragma unroll
            for (int j = 0; j < 8; ++j) {
                int d = ks * 32 + hi * 8 + j;
                float v = 0.f;
                if (d < DDIM) {
                    int p  = d / WINW;
                    int w  = d - p * WINW;
                    int tt = t + w - PADW;
                    if (tt >= 0 && tt < TDIM) v = xb[p * TDIM + tt];
                }
                a[j] = (short)f2bf(v);
            }
            afr[ks] = a;
        }
    }

    // ---- Sweep codes: 64 N-tiles of 16 codes ----
    float bs[4];
    int   bi[4];
#pragma unroll
    for (int r = 0; r < 4; ++r) { bs[r] = -3.0e38f; bi[r] = 0; }

    for (int nt = 0; nt < NTILES; ++nt) {
        f32x4 acc = {0.f, 0.f, 0.f, 0.f};
        const short8* bp = (const short8*)bfrag + (size_t)(nt * KSTEPS) * 64 + lane;
#pragma unroll
        for (int ks = 0; ks < KSTEPS; ++ks) {
            short8 bfr = bp[ks * 64];
            acc = __builtin_amdgcn_mfma_f32_16x16x32_bf16(afr[ks], bfr, acc, 0, 0, 0);
        }
        int n = nt * 16 + ld;                 // code index this lane scored
        float sb = -0.5f * cnorm[n];
#pragma unroll
        for (int r = 0; r < 4; ++r) {         // D: col(N)=lane&15, row(M)=hi*4+r
            float s = acc[r] + sb;
            if (s > bs[r]) { bs[r] = s; bi[r] = n; }   // strict > keeps first (lowest n)
        }
    }

    // ---- Cross-lane argmax within each 16-lane group (xor masks stay in-group) ----
#pragma unroll
    for (int msk = 1; msk < 16; msk <<= 1) {
#pragma unroll
        for (int r = 0; r < 4; ++r) {
            float os = __shfl_xor(bs[r], msk, 64);
            int   oi = __shfl_xor(bi[r], msk, 64);
            if (os > bs[r] || (os == bs[r] && oi < bi[r])) { bs[r] = os; bi[r] = oi; }
        }
    }

    // ---- Exact fp32 distance for the chosen code; group's 16 lanes split D ----
    float dsum = 0.f;
#pragma unroll
    for (int r = 0; r < 4; ++r) {
        int row = rowbase + hi * 4 + r;
        int enc = bi[r];
        int b = row >> 12;
        int t = row & (TDIM - 1);
        const float* xb   = x + (size_t)b * (PDIM * TDIM);
        const float* crow = cb + (size_t)enc * DDIM;
        float s = 0.f;
        for (int d = ld; d < DDIM; d += 16) {
            int p  = d / WINW;
            int w  = d - p * WINW;
            int tt = t + w - PADW;
            float fv = (tt >= 0 && tt < TDIM) ? xb[p * TDIM + tt] : 0.f;
            float diff = fv - crow[d];
            s += diff * diff;
        }
        dsum += s;
    }
#pragma unroll
    for (int msk = 1; msk < 16; msk <<= 1) dsum += __shfl_xor(dsum, msk, 64);

    __shared__ float gsum[16];
    if (ld == 0) gsum[wave * 4 + hi] = dsum;
    __syncthreads();
    if (threadIdx.x == 0) {
        float tot = 0.f;
#pragma unroll
        for (int i = 0; i < 16; ++i) tot += gsum[i];
        bsum[blockIdx.x] = tot;
    }
}

__global__ __launch_bounds__(256) void finalize_k(const float* __restrict__ bsum,
                                                  float* __restrict__ out) {
    __shared__ double sm[256];
    double s = 0.0;
    for (int i = threadIdx.x; i < 1024; i += 256) s += (double)bsum[i];
    sm[threadIdx.x] = s;
    __syncthreads();
    for (int st = 128; st > 0; st >>= 1) {
        if ((int)threadIdx.x < st) sm[threadIdx.x] += sm[threadIdx.x + st];
        __syncthreads();
    }
    if (threadIdx.x == 0)
        out[0] = (float)(0.25 * sm[0] / ((double)65536 * (double)DDIM));
}

extern "C" void kernel_launch(void* const* d_in, const int* in_sizes, int n_in,
                              void* d_out, int out_size, void* d_ws, size_t ws_size,
                              hipStream_t stream) {
    const float* x  = (const float*)d_in[0];   // (16,12,4096) f32
    const float* cb = (const float*)d_in[1];   // (1024,492) f32
    float* out = (float*)d_out;

    // workspace layout
    unsigned short* bfrag = (unsigned short*)d_ws;                       // 1 MiB
    float* cnorm = (float*)((char*)d_ws + (1u << 20));                   // 4 KiB
    float* bsum  = (float*)((char*)d_ws + (1u << 20) + 4096);            // 4 KiB

    prep_bfrag_k<<<256, 256, 0, stream>>>(cb, bfrag);
    prep_cnorm_k<<<KCODES, 64, 0, stream>>>(cb, cnorm);
    vq_main_k<<<65536 / BM, 256, 0, stream>>>(x, cb, bfrag, cnorm, bsum);
    finalize_k<<<1, 256, 0, stream>>>(bsum, out);
}

// Round 2
// 169.021 us; speedup vs baseline: 1.3984x; 1.3984x over previous
//
#include <hip/hip_runtime.h>

// Problem constants
#define BDIM   16
#define PDIM   12
#define TDIM   4096
#define WINW   41
#define PADW   20
#define DDIM   492      // P*WIN
#define DPAD   512      // padded K for MFMA (zeros beyond 492)
#define KCODES 1024
#define KSTEPS 16       // 512 / 32
#define NTILES 64       // 1024 / 16

#define WAVES      8
#define ROWS_WAVE  32               // 2 slabs of 16 rows
#define BMROWS     (WAVES * ROWS_WAVE)   // 256 rows per block
#define CHUNK_NT   4                // ntiles staged per chunk
#define NCHUNK     (NTILES / CHUNK_NT)   // 16
#define NT_BYTES   (KSTEPS * 64 * 16)    // 16384 bytes per ntile
#define CHUNK_BYTES (CHUNK_NT * NT_BYTES) // 65536

typedef __attribute__((ext_vector_type(8))) short  short8;  // 8 x bf16 (4 VGPRs)
typedef __attribute__((ext_vector_type(4))) float  f32x4;   // MFMA acc

__device__ __forceinline__ unsigned short f2bf(float f) {
    union { float f; unsigned int u; } v; v.f = f;
    unsigned int r = v.u + 0x7FFFu + ((v.u >> 16) & 1u);  // round-to-nearest-even
    return (unsigned short)(r >> 16);
}

// Pre-format codebook into B-fragment order for mfma_f32_16x16x32_bf16.
// Layout: frag index idx = (nt*16 + ks)*64 + lane, each holding 8 bf16:
//   B[k][n] with n = nt*16 + (lane&15), k = ks*32 + (lane>>4)*8 + j
__global__ __launch_bounds__(256) void prep_bfrag_k(const float* __restrict__ cb,
                                                    unsigned short* __restrict__ bfrag) {
    int idx  = blockIdx.x * 256 + threadIdx.x;   // 0 .. 65535
    int lane = idx & 63;
    int ks   = (idx >> 6) & 15;
    int nt   = idx >> 10;
    int n    = nt * 16 + (lane & 15);
    int hi   = lane >> 4;
    short8 sv;
#pragma unroll
    for (int j = 0; j < 8; ++j) {
        int k = ks * 32 + hi * 8 + j;
        float f = (k < DDIM) ? cb[n * DDIM + k] : 0.f;
        sv[j] = (short)f2bf(f);
    }
    *(short8*)(bfrag + (size_t)idx * 8) = sv;
}

__global__ __launch_bounds__(64) void prep_cnorm_k(const float* __restrict__ cb,
                                                   float* __restrict__ cnorm) {
    int n = blockIdx.x;
    int lane = threadIdx.x;
    float s = 0.f;
    for (int d = lane; d < DDIM; d += 64) { float c = cb[n * DDIM + d]; s += c * c; }
#pragma unroll
    for (int m = 1; m < 64; m <<= 1) s += __shfl_xor(s, m, 64);
    if (lane == 0) cnorm[n] = s;
}

// Stage one 64 KiB chunk of bfrag into LDS via async global->LDS (width 16).
// LDS dest is wave-uniform base + lane*16; bfrag is already in that linear order.
__device__ __forceinline__ void stage_chunk(const unsigned short* __restrict__ bfrag,
                                            unsigned char* smem_buf, int chunk,
                                            int wave, int lane) {
    const unsigned char* gsrc = (const unsigned char*)bfrag + (size_t)chunk * CHUNK_BYTES;
#pragma unroll
    for (int it = 0; it < 8; ++it) {
        int off = it * 8192 + wave * 1024;
        __builtin_amdgcn_global_load_lds(
            (const __attribute__((address_space(1))) unsigned int*)(gsrc + off + lane * 16),
            (__attribute__((address_space(3))) unsigned int*)(smem_buf + off),
            16, 0, 0);
    }
}

// Main: block = 8 waves x 32 rows = 256 rows. Each wave keeps 2 A-slabs
// (16 rows x 512 dims bf16) in registers; B streamed through double-buffered
// LDS. Score = f.c - 0.5*||c||^2 (argmax == argmin dist). Selected distance
// recomputed exactly in fp32; per-block partial sum out.
__global__ __launch_bounds__(512, 2) void vq_main_k(const float* __restrict__ x,
                                                    const float* __restrict__ cb,
                                                    const unsigned short* __restrict__ bfrag,
                                                    const float* __restrict__ cnorm,
                                                    float* __restrict__ bsum) {
    __shared__ unsigned char smem[2][CHUNK_BYTES];
    __shared__ float gsum[WAVES];

    const int lane = threadIdx.x & 63;
    const int wave = threadIdx.x >> 6;
    const int ld   = lane & 15;
    const int hi   = lane >> 4;
    const int rowbase = blockIdx.x * BMROWS + wave * ROWS_WAVE;

    // Kick off staging of chunk 0 ASAP; A-build overlaps the load latency.
    stage_chunk(bfrag, smem[0], 0, wave, lane);

    // ---- Build A fragments for 2 slabs (row = rowbase + s*16 + ld) ----
    short8 afr[2][KSTEPS];
#pragma unroll
    for (int s = 0; s < 2; ++s) {
        int m = rowbase + s * 16 + ld;
        int b = m >> 12;            // / TDIM
        int t = m & (TDIM - 1);
        const float* xb = x + (size_t)b * (PDIM * TDIM);
#pragma unroll
        for (int ks = 0; ks < KSTEPS; ++ks) {
            short8 a;
#pragma unroll
            for (int j = 0; j < 8; ++j) {
                int d = ks * 32 + hi * 8 + j;
                float v = 0.f;
                if (d < DDIM) {
                    int p  = d / WINW;
                    int w  = d - p * WINW;
                    int tt = t + w - PADW;
                    if (tt >= 0 && tt < TDIM) v = xb[p * TDIM + tt];
                }
                a[j] = (short)f2bf(v);
            }
            afr[s][ks] = a;
        }
    }

    float bs[2][4];
    int   bi[2][4];
#pragma unroll
    for (int s = 0; s < 2; ++s)
#pragma unroll
        for (int r = 0; r < 4; ++r) { bs[s][r] = -3.0e38f; bi[s][r] = 0; }

    __syncthreads();   // chunk 0 resident (barrier drains vmcnt)

    // ---- Sweep codes: 16 chunks x 4 ntiles x 16 codes ----
    for (int c = 0; c < NCHUNK; ++c) {
        if (c + 1 < NCHUNK) stage_chunk(bfrag, smem[(c + 1) & 1], c + 1, wave, lane);
        const unsigned char* cur = smem[c & 1];
#pragma unroll
        for (int ntl = 0; ntl < CHUNK_NT; ++ntl) {
            const int nt = c * CHUNK_NT + ntl;
            f32x4 acc0 = {0.f, 0.f, 0.f, 0.f};
            f32x4 acc1 = {0.f, 0.f, 0.f, 0.f};
            const short8* bp = (const short8*)cur + (ntl * KSTEPS) * 64 + lane;
#pragma unroll
            for (int ks = 0; ks < KSTEPS; ++ks) {
                short8 bfr = bp[ks * 64];
                acc0 = __builtin_amdgcn_mfma_f32_16x16x32_bf16(afr[0][ks], bfr, acc0, 0, 0, 0);
                acc1 = __builtin_amdgcn_mfma_f32_16x16x32_bf16(afr[1][ks], bfr, acc1, 0, 0, 0);
            }
            const int n = nt * 16 + ld;             // code index this lane scored
            const float sb = -0.5f * cnorm[n];
#pragma unroll
            for (int r = 0; r < 4; ++r) {           // D: col(N)=lane&15, row(M)=hi*4+r
                float s0 = acc0[r] + sb;
                float s1 = acc1[r] + sb;
                if (s0 > bs[0][r]) { bs[0][r] = s0; bi[0][r] = n; }
                if (s1 > bs[1][r]) { bs[1][r] = s1; bi[1][r] = n; }
            }
        }
        __syncthreads();   // staging of c+1 done; all waves done reading cur
    }

    // ---- Cross-lane argmax within each 16-lane group ----
#pragma unroll
    for (int msk = 1; msk < 16; msk <<= 1) {
#pragma unroll
        for (int s = 0; s < 2; ++s)
#pragma unroll
            for (int r = 0; r < 4; ++r) {
                float os = __shfl_xor(bs[s][r], msk, 64);
                int   oi = __shfl_xor(bi[s][r], msk, 64);
                if (os > bs[s][r] || (os == bs[s][r] && oi < bi[s][r])) {
                    bs[s][r] = os; bi[s][r] = oi;
                }
            }
    }

    // ---- Exact fp32 distance for chosen codes; 16 lanes of each group split D ----
    float dsum = 0.f;
#pragma unroll
    for (int s = 0; s < 2; ++s)
#pragma unroll
    for (int r = 0; r < 4; ++r) {
        int row = rowbase + s * 16 + hi * 4 + r;
        int enc = bi[s][r];
        int b = row >> 12;
        int t = row & (TDIM - 1);
        const float* xb   = x + (size_t)b * (PDIM * TDIM);
        const float* crow = cb + (size_t)enc * DDIM;
        float ss = 0.f;
        for (int d = ld; d < DDIM; d += 16) {
            int p  = d / WINW;
            int w  = d - p * WINW;
            int tt = t + w - PADW;
            float fv = (tt >= 0 && tt < TDIM) ? xb[p * TDIM + tt] : 0.f;
            float diff = fv - crow[d];
            ss += diff * diff;
        }
        dsum += ss;
    }
#pragma unroll
    for (int msk = 1; msk < 64; msk <<= 1) dsum += __shfl_xor(dsum, msk, 64);

    if (lane == 0) gsum[wave] = dsum;
    __syncthreads();
    if (threadIdx.x == 0) {
        float tot = 0.f;
#pragma unroll
        for (int i = 0; i < WAVES; ++i) tot += gsum[i];
        bsum[blockIdx.x] = tot;
    }
}

__global__ __launch_bounds__(256) void finalize_k(const float* __restrict__ bsum,
                                                  float* __restrict__ out) {
    __shared__ double sm[256];
    double s = 0.0;
    for (int i = threadIdx.x; i < 256; i += 256) s += (double)bsum[i];
    sm[threadIdx.x] = s;
    __syncthreads();
    for (int st = 128; st > 0; st >>= 1) {
        if ((int)threadIdx.x < st) sm[threadIdx.x] += sm[threadIdx.x + st];
        __syncthreads();
    }
    if (threadIdx.x == 0)
        out[0] = (float)(0.25 * sm[0] / ((double)65536 * (double)DDIM));
}

extern "C" void kernel_launch(void* const* d_in, const int* in_sizes, int n_in,
                              void* d_out, int out_size, void* d_ws, size_t ws_size,
                              hipStream_t stream) {
    const float* x  = (const float*)d_in[0];   // (16,12,4096) f32
    const float* cb = (const float*)d_in[1];   // (1024,492) f32
    float* out = (float*)d_out;

    // workspace layout
    unsigned short* bfrag = (unsigned short*)d_ws;                       // 1 MiB
    float* cnorm = (float*)((char*)d_ws + (1u << 20));                   // 4 KiB
    float* bsum  = (float*)((char*)d_ws + (1u << 20) + 4096);            // 1 KiB

    prep_bfrag_k<<<256, 256, 0, stream>>>(cb, bfrag);
    prep_cnorm_k<<<KCODES, 64, 0, stream>>>(cb, cnorm);
    vq_main_k<<<65536 / BMROWS, 512, 0, stream>>>(x, cb, bfrag, cnorm, bsum);
    finalize_k<<<1, 256, 0, stream>>>(bsum, out);
}